// Round 16
// baseline (122.826 us; speedup 1.0000x reference)
//
#include <hip/hip_runtime.h>
#include <cstddef>

typedef float f32x4 __attribute__((ext_vector_type(4)));
typedef short s16x4 __attribute__((ext_vector_type(4)));
typedef short s16x8 __attribute__((ext_vector_type(8)));
typedef __bf16 bf16x8 __attribute__((ext_vector_type(8)));

#define NB 8
#define NS 1024
#define ND 768
#define NH 12
#define HD 64

__device__ __forceinline__ unsigned short f2bf(float f) {
  unsigned u = __builtin_bit_cast(unsigned, f);
  u += 0x7fffu + ((u >> 16) & 1u);
  return (unsigned short)(u >> 16);
}

__device__ __forceinline__ f32x4 mfma16(bf16x8 a, bf16x8 b, f32x4 c) {
  return __builtin_amdgcn_mfma_f32_16x16x32_bf16(a, b, c, 0, 0, 0);
}

__device__ __forceinline__ bf16x8 ld8(const unsigned short* p) {
  return *reinterpret_cast<const bf16x8*>(p);
}

__device__ __forceinline__ void gload16(unsigned short* lds_dst, const unsigned short* gsrc) {
  __builtin_amdgcn_global_load_lds(
      (const __attribute__((address_space(1))) unsigned int*)gsrc,
      (__attribute__((address_space(3))) unsigned int*)lds_dst, 16, 0, 0);
}

#define VMW(N) asm volatile("s_waitcnt vmcnt(" #N ")" ::: "memory")

// ---------------- pack kernels ----------------

__global__ __launch_bounds__(256) void cvt_f32_bf16(const float* __restrict__ in,
                                                    unsigned short* __restrict__ out) {
  int i = (blockIdx.x * 256 + threadIdx.x) * 4;
  float4 v = *reinterpret_cast<const float4*>(in + i);
  ushort4 o;
  o.x = f2bf(v.x); o.y = f2bf(v.y); o.z = f2bf(v.z); o.w = f2bf(v.w);
  *reinterpret_cast<ushort4*>(out + i) = o;
}

__global__ __launch_bounds__(256) void transpose_cvt(const float* __restrict__ in,
                                                     unsigned short* __restrict__ out,
                                                     int R, int C) {
  __shared__ float tile[32][33];
  int c0 = blockIdx.x * 32, r0 = blockIdx.y * 32;
  int tx = threadIdx.x & 31, ty = threadIdx.x >> 5;
#pragma unroll
  for (int i = 0; i < 32; i += 8)
    tile[ty + i][tx] = in[(size_t)(r0 + ty + i) * C + c0 + tx];
  __syncthreads();
#pragma unroll
  for (int i = 0; i < 32; i += 8)
    out[(size_t)(c0 + ty + i) * R + r0 + tx] = f2bf(tile[tx][ty + i]);
}

// ---------------- GEMM mainloops (verified disciplines) ----------------

#define SLOT 8192  // shorts per slot: A[128][32] + B[128][32]

// depth-3, 4-slot (r11/r13-verified: qkv 58us, FETCH/WRITE at ideal)
__device__ __forceinline__ void gemm_mainloop4(const unsigned short* __restrict__ A,
                                               const unsigned short* __restrict__ Bt,
                                               int K, int m0, int n0,
                                               unsigned short* smem,
                                               f32x4 (&acc)[4][4]) {
  int tid = threadIdx.x, lane = tid & 63, wid = tid >> 6;
  int wr = wid >> 1, wc = wid & 1;
  int ll = lane & 15, lh = lane >> 4;
  int swsrc = ((lane & 3) ^ ((lane >> 3) & 3)) * 8;

  const unsigned short* asrc = A + (size_t)(m0 + wid * 32 + (lane >> 2)) * K + swsrc;
  const unsigned short* bsrc = Bt + (size_t)(n0 + wid * 32 + (lane >> 2)) * K + swsrc;
  const int sw = (lh ^ ((ll >> 1) & 3)) * 8;
  const int nt = K / 32;  // 24

  auto stage = [&](int slot, int t) {
    unsigned short* ad = smem + slot * SLOT + wid * 1024;
    unsigned short* bd = smem + slot * SLOT + 4096 + wid * 1024;
    const unsigned short* as = asrc + t * 32;
    const unsigned short* bs = bsrc + t * 32;
    gload16(ad, as);
    gload16(ad + 512, as + (size_t)16 * K);
    gload16(bd, bs);
    gload16(bd + 512, bs + (size_t)16 * K);
  };

  stage(0, 0);
  stage(1, 1);
  stage(2, 2);
  VMW(8);
  __builtin_amdgcn_s_barrier();
  asm volatile("" ::: "memory");

  for (int t = 0; t < nt; ++t) {
    if (t + 3 < nt) stage((t + 3) & 3, t + 3);

    const unsigned short* Ab = smem + (t & 3) * SLOT;
    const unsigned short* Bb = Ab + 4096;

    __builtin_amdgcn_s_setprio(1);
    bf16x8 af[4], bg[4];
#pragma unroll
    for (int m = 0; m < 4; m++) af[m] = ld8(Ab + (wr * 64 + m * 16 + ll) * 32 + sw);
#pragma unroll
    for (int n = 0; n < 4; n++) bg[n] = ld8(Bb + (wc * 64 + n * 16 + ll) * 32 + sw);
#pragma unroll
    for (int m = 0; m < 4; m++)
#pragma unroll
      for (int n = 0; n < 4; n++) acc[m][n] = mfma16(af[m], bg[n], acc[m][n]);
    __builtin_amdgcn_s_setprio(0);

    if (t + 3 < nt) {
      VMW(8);
      __builtin_amdgcn_s_barrier();
      asm volatile("" ::: "memory");
    } else if (t + 2 < nt) {
      VMW(4);
      __builtin_amdgcn_s_barrier();
      asm volatile("" ::: "memory");
    } else if (t + 1 < nt) {
      VMW(0);
      __builtin_amdgcn_s_barrier();
      asm volatile("" ::: "memory");
    }
  }
}

// depth-2, 3-slot (r10-verified)
__device__ __forceinline__ void gemm_mainloop3(const unsigned short* __restrict__ A,
                                               const unsigned short* __restrict__ Bt,
                                               int K, int m0, int n0,
                                               unsigned short* smem,
                                               f32x4 (&acc)[4][4]) {
  int tid = threadIdx.x, lane = tid & 63, wid = tid >> 6;
  int wr = wid >> 1, wc = wid & 1;
  int ll = lane & 15, lh = lane >> 4;
  int swsrc = ((lane & 3) ^ ((lane >> 3) & 3)) * 8;

  const unsigned short* asrc = A + (size_t)(m0 + wid * 32 + (lane >> 2)) * K + swsrc;
  const unsigned short* bsrc = Bt + (size_t)(n0 + wid * 32 + (lane >> 2)) * K + swsrc;
  const int sw = (lh ^ ((ll >> 1) & 3)) * 8;
  const int nt = K / 32;

  auto stage = [&](int slot, int t) {
    unsigned short* ad = smem + slot * SLOT + wid * 1024;
    unsigned short* bd = smem + slot * SLOT + 4096 + wid * 1024;
    const unsigned short* as = asrc + t * 32;
    const unsigned short* bs = bsrc + t * 32;
    gload16(ad, as);
    gload16(ad + 512, as + (size_t)16 * K);
    gload16(bd, bs);
    gload16(bd + 512, bs + (size_t)16 * K);
  };

  stage(0, 0);
  stage(1, 1);
  VMW(4);
  __builtin_amdgcn_s_barrier();
  asm volatile("" ::: "memory");

  int slot = 0;
  for (int t = 0; t < nt; ++t) {
    if (t + 2 < nt) {
      int s2 = slot + 2; if (s2 >= 3) s2 -= 3;
      stage(s2, t + 2);
    }
    const unsigned short* Ab = smem + slot * SLOT;
    const unsigned short* Bb = Ab + 4096;

    __builtin_amdgcn_s_setprio(1);
    bf16x8 af[4], bg[4];
#pragma unroll
    for (int m = 0; m < 4; m++) af[m] = ld8(Ab + (wr * 64 + m * 16 + ll) * 32 + sw);
#pragma unroll
    for (int n = 0; n < 4; n++) bg[n] = ld8(Bb + (wc * 64 + n * 16 + ll) * 32 + sw);
#pragma unroll
    for (int m = 0; m < 4; m++)
#pragma unroll
      for (int n = 0; n < 4; n++) acc[m][n] = mfma16(af[m], bg[n], acc[m][n]);
    __builtin_amdgcn_s_setprio(0);

    if (t + 2 < nt) {
      VMW(4);
      __builtin_amdgcn_s_barrier();
      asm volatile("" ::: "memory");
    } else if (t + 2 == nt) {
      VMW(0);
      __builtin_amdgcn_s_barrier();
      asm volatile("" ::: "memory");
    }
    slot++; if (slot == 3) slot = 0;
  }
}

// ---------------- QKV GEMM (fused V-transpose epilogue; q pre-scaled into log2 domain) ----------------

#define QSCALE 0.18033688f  // 0.125 * log2(e): softmax then uses exp2 directly

__global__ __launch_bounds__(256, 2) void qkv_gemm(const unsigned short* __restrict__ xbf,
                                                   const unsigned short* __restrict__ WT,
                                                   const float* __restrict__ bias,
                                                   unsigned short* __restrict__ qw,
                                                   unsigned short* __restrict__ kw,
                                                   unsigned short* __restrict__ vt) {
  __shared__ __align__(16) unsigned short smem[4 * SLOT];
  int bid = blockIdx.x;
  int k8 = bid & 7, j = bid >> 3;
  int m0 = (k8 * 8 + (j & 7)) * 128;
  int n0 = (j >> 3) * 128;
  f32x4 acc[4][4];
#pragma unroll
  for (int m = 0; m < 4; m++)
#pragma unroll
    for (int n = 0; n < 4; n++) acc[m][n] = (f32x4){0.f, 0.f, 0.f, 0.f};

  gemm_mainloop4(xbf, WT, ND, m0, n0, smem, acc);

  int tid = threadIdx.x, lane = tid & 63, wid = tid >> 6;
  int wr = wid >> 1, wc = wid & 1;
  int ll = lane & 15, lh = lane >> 4;
  int which = n0 / ND;  // block-uniform

  if (which == 2) {
#pragma unroll
    for (int nf = 0; nf < 4; nf++) {
      int col = n0 + wc * 64 + nf * 16 + ll;
      float bv = bias[col];
      int w2 = col - 2 * ND;
      int h = w2 >> 6, d = w2 & 63;
#pragma unroll
      for (int mf = 0; mf < 4; mf++) {
        int m = m0 + wr * 64 + mf * 16 + lh * 4;
        int b = m >> 10, s = m & 1023;
        s16x4 pk;
        pk[0] = (short)f2bf(acc[mf][nf][0] + bv);
        pk[1] = (short)f2bf(acc[mf][nf][1] + bv);
        pk[2] = (short)f2bf(acc[mf][nf][2] + bv);
        pk[3] = (short)f2bf(acc[mf][nf][3] + bv);
        size_t idx = (((size_t)b * NH + h) * HD + d) * NS + s;
        *(s16x4*)&vt[idx] = pk;
      }
    }
  } else {
#pragma unroll
    for (int nf = 0; nf < 4; nf++) {
      int col = n0 + wc * 64 + nf * 16 + ll;
      float bv = bias[col];
      int w2 = col - which * ND;
      int h = w2 >> 6, d = w2 & 63;
#pragma unroll
      for (int mf = 0; mf < 4; mf++) {
#pragma unroll
        for (int r = 0; r < 4; r++) {
          int m = m0 + wr * 64 + mf * 16 + lh * 4 + r;
          int b = m >> 10, s = m & 1023;
          float v = acc[mf][nf][r] + bv;
          size_t idx = (((size_t)b * NH + h) * NS + s) * HD + d;
          if (which == 0)
            qw[idx] = f2bf(v * QSCALE);
          else
            kw[idx] = f2bf(v);
        }
      }
    }
  }
}

// ---------------- proj GEMM ----------------

__global__ __launch_bounds__(256, 3) void proj_gemm(const unsigned short* __restrict__ abf,
                                                    const unsigned short* __restrict__ WT,
                                                    const float* __restrict__ bias,
                                                    float* __restrict__ out) {
  __shared__ __align__(16) unsigned short smem[3 * SLOT];
  int bid = blockIdx.x;
  int k8 = bid & 7, j = bid >> 3;
  int m0 = (k8 * 8 + (j & 7)) * 128;
  int n0 = (j >> 3) * 128;
  f32x4 acc[4][4];
#pragma unroll
  for (int m = 0; m < 4; m++)
#pragma unroll
    for (int n = 0; n < 4; n++) acc[m][n] = (f32x4){0.f, 0.f, 0.f, 0.f};

  gemm_mainloop3(abf, WT, ND, m0, n0, smem, acc);

  int tid = threadIdx.x, lane = tid & 63, wid = tid >> 6;
  int wr = wid >> 1, wc = wid & 1;
  int ll = lane & 15, lh = lane >> 4;
#pragma unroll
  for (int nf = 0; nf < 4; nf++) {
    int col = n0 + wc * 64 + nf * 16 + ll;
    float bv = bias[col];
#pragma unroll
    for (int mf = 0; mf < 4; mf++) {
#pragma unroll
      for (int r = 0; r < 4; r++) {
        int m = m0 + wr * 64 + mf * 16 + lh * 4 + r;
        out[(size_t)m * ND + col] = acc[mf][nf][r] + bv;
      }
    }
  }
}

// ---------------- flash attention: QBLK=256, two 16-row groups/wave share staged tiles ----------------
// Grid 384 = 8 XCD x (12 heads x 4 q-tiles); XCD k owns heads [12k,12k+12) -> K/V
// L2-resident (3 MB < 4 MB). Each wave owns 32 q-rows as two sequential 16-row
// groups (g=0,1) computed against the SAME staged K/V tile: staged-tile count and
// barrier count per unit compute halve (6912 -> 3840 tiles grid-wide, 0.56x).
// Group skip decision provably equal for both groups at 64-aligned j0 -> single
// wave-uniform skip on qmaxw = q0w+31. Ps reused sequentially by groups (in-wave
// LDS ordering, no barrier). Staging/pipeline discipline identical to r13.

#define LP 88          // Ps row stride (shorts)
#define KVSLOT 8192    // shorts: K[64][64] + V[64][64]

__global__ __launch_bounds__(512) void attn_kernel(const unsigned short* __restrict__ qw,
                                                   const unsigned short* __restrict__ kw,
                                                   const unsigned short* __restrict__ vt,
                                                   unsigned short* __restrict__ attn_out) {
  int bid = blockIdx.x;
  int xcd = bid & 7, j = bid >> 3;        // j in [0,48)
  int grp = xcd * 12 + (j % 12);          // bh group: 12 heads per XCD
  int qt = 3 - (j / 12);                  // heavy q-tiles first (qt=3 has nt=16)
  int b = grp / NH, h = grp % NH;
  __shared__ __align__(16) unsigned short KV[3 * KVSLOT];
  __shared__ __align__(16) unsigned short Ps[8][16 * LP];

  int tid = threadIdx.x, lane = tid & 63, wid = tid >> 6;
  int ll = lane & 15, lh = lane >> 4, r7x = ll & 7;
  int q0 = qt * 256, q0w = q0 + wid * 32;  // wave owns 32 q-rows
  const size_t bhk = ((size_t)b * NH + h) * NS * HD;
  const size_t bhv = ((size_t)b * NH + h) * HD * NS;

  // Q fragments for both 16-row groups
  bf16x8 qf[2][2];
#pragma unroll
  for (int g = 0; g < 2; g++) {
    qf[g][0] = ld8(&qw[bhk + (size_t)(q0w + g * 16 + ll) * HD + lh * 8]);
    qf[g][1] = ld8(&qw[bhk + (size_t)(q0w + g * 16 + ll) * HD + 32 + lh * 8]);
  }

  f32x4 o[2][4];
#pragma unroll
  for (int g = 0; g < 2; g++)
#pragma unroll
    for (int n = 0; n < 4; n++) o[g][n] = (f32x4){0.f, 0.f, 0.f, 0.f};
  float m_r[2] = {-1e30f, -1e30f}, l_r[2] = {0.f, 0.f};

  int srow = tid >> 3;
  int scol = ((tid & 7) ^ ((tid >> 3) & 7)) * 8;
  const unsigned short* ksrc = kw + bhk + (size_t)srow * HD + scol;
  const unsigned short* vsrc = vt + bhv + (size_t)srow * NS + scol;

  unsigned short* pw = &Ps[wid][ll * LP];
  const int qmaxw = q0w + 31;             // single skip bound (both groups agree)
  const int nt = 4 * (qt + 1);            // >= 4

  auto stage = [&](int slot, int t) {
    unsigned short* kd = KV + slot * KVSLOT + wid * 512;
    unsigned short* vd = KV + slot * KVSLOT + 4096 + wid * 512;
    gload16(kd, ksrc + (size_t)t * 64 * HD);
    gload16(vd, vsrc + t * 64);
  };

  stage(0, 0);
  stage(1, 1);
  VMW(2);
  __builtin_amdgcn_s_barrier();
  asm volatile("" ::: "memory");

  int slot = 0;
  for (int t = 0; t < nt; ++t) {
    if (t + 2 < nt) {
      int s2 = slot + 2; if (s2 >= 3) s2 -= 3;
      stage(s2, t + 2);
    }
    int j0 = t * 64;

    if (j0 <= qmaxw) {
      const unsigned short* Kb = KV + slot * KVSLOT;
      const unsigned short* Vb = Kb + 4096;

#pragma unroll
      for (int g = 0; g < 2; g++) {
        // S^T = K Q^T for this row group
        f32x4 sa[4];
#pragma unroll
        for (int n = 0; n < 4; n++) {
          bf16x8 kf0 = ld8(Kb + (n * 16 + ll) * 64 + (lh ^ r7x) * 8);
          bf16x8 kf1 = ld8(Kb + (n * 16 + ll) * 64 + ((4 + lh) ^ r7x) * 8);
          sa[n] = mfma16(kf0, qf[g][0], (f32x4){0.f, 0.f, 0.f, 0.f});
          sa[n] = mfma16(kf1, qf[g][1], sa[n]);
        }

        int qbase = q0w + g * 16;
        if (j0 + 63 > qbase) {  // diagonal tile: causal mask
          int qme = qbase + ll;
#pragma unroll
          for (int n = 0; n < 4; n++)
#pragma unroll
            for (int r = 0; r < 4; r++)
              if (j0 + n * 16 + lh * 4 + r > qme) sa[n][r] = -1e30f;
        }

        float t0 = fmaxf(fmaxf(sa[0][0], sa[0][1]), fmaxf(sa[0][2], sa[0][3]));
        float t1 = fmaxf(fmaxf(sa[1][0], sa[1][1]), fmaxf(sa[1][2], sa[1][3]));
        float t2 = fmaxf(fmaxf(sa[2][0], sa[2][1]), fmaxf(sa[2][2], sa[2][3]));
        float t3 = fmaxf(fmaxf(sa[3][0], sa[3][1]), fmaxf(sa[3][2], sa[3][3]));
        float tmax = fmaxf(fmaxf(t0, t1), fmaxf(t2, t3));
        tmax = fmaxf(tmax, __shfl_xor(tmax, 16));
        tmax = fmaxf(tmax, __shfl_xor(tmax, 32));

        // defer-max (log2 domain): skip rescale while growth <= 11.5
        if (!__all(tmax - m_r[g] <= 11.5f)) {
          float mnew = fmaxf(m_r[g], tmax);
          float alpha = exp2f(m_r[g] - mnew);
          m_r[g] = mnew;
          l_r[g] *= alpha;
          float ab0 = __shfl(alpha, lh * 4 + 0);
          float ab1 = __shfl(alpha, lh * 4 + 1);
          float ab2 = __shfl(alpha, lh * 4 + 2);
          float ab3 = __shfl(alpha, lh * 4 + 3);
#pragma unroll
          for (int n2 = 0; n2 < 4; n2++) {
            o[g][n2][0] *= ab0; o[g][n2][1] *= ab1;
            o[g][n2][2] *= ab2; o[g][n2][3] *= ab3;
          }
        }

        float p[4][4];
        float ssum = 0.f;
#pragma unroll
        for (int n = 0; n < 4; n++)
#pragma unroll
          for (int r = 0; r < 4; r++) {
            p[n][r] = exp2f(sa[n][r] - m_r[g]);
            ssum += p[n][r];
          }
        ssum += __shfl_xor(ssum, 16);
        ssum += __shfl_xor(ssum, 32);
        l_r[g] += ssum;

#pragma unroll
        for (int n = 0; n < 4; n++) {
          s16x4 pk;
          pk[0] = (short)f2bf(p[n][0]);
          pk[1] = (short)f2bf(p[n][1]);
          pk[2] = (short)f2bf(p[n][2]);
          pk[3] = (short)f2bf(p[n][3]);
          *(s16x4*)&pw[n * 16 + lh * 4] = pk;
        }

#pragma unroll
        for (int c = 0; c < 2; c++) {
          bf16x8 pf = ld8(&pw[c * 32 + lh * 8]);
#pragma unroll
          for (int n2 = 0; n2 < 4; n2++) {
            bf16x8 vf = ld8(Vb + (n2 * 16 + ll) * 64 + ((c * 4 + lh) ^ r7x) * 8);
            o[g][n2] = mfma16(pf, vf, o[g][n2]);
          }
        }
      }
    }

    if (t + 2 < nt) {
      VMW(2);
      __builtin_amdgcn_s_barrier();
      asm volatile("" ::: "memory");
    } else if (t + 2 == nt) {
      VMW(0);
      __builtin_amdgcn_s_barrier();
      asm volatile("" ::: "memory");
    }
    slot++; if (slot == 3) slot = 0;
  }

  // epilogue: normalize + store merged heads [B,S,D]
#pragma unroll
  for (int g = 0; g < 2; g++) {
    float lrec = 1.0f / l_r[g];
    float lb0 = __shfl(lrec, lh * 4 + 0);
    float lb1 = __shfl(lrec, lh * 4 + 1);
    float lb2 = __shfl(lrec, lh * 4 + 2);
    float lb3 = __shfl(lrec, lh * 4 + 3);
#pragma unroll
    for (int n2 = 0; n2 < 4; n2++) {
      int d = n2 * 16 + ll;
      int qb = q0w + g * 16 + lh * 4;
      attn_out[((size_t)b * NS + qb + 0) * ND + h * HD + d] = f2bf(o[g][n2][0] * lb0);
      attn_out[((size_t)b * NS + qb + 1) * ND + h * HD + d] = f2bf(o[g][n2][1] * lb1);
      attn_out[((size_t)b * NS + qb + 2) * ND + h * HD + d] = f2bf(o[g][n2][2] * lb2);
      attn_out[((size_t)b * NS + qb + 3) * ND + h * HD + d] = f2bf(o[g][n2][3] * lb3);
    }
  }
}

// ---------------- launch ----------------

extern "C" void kernel_launch(void* const* d_in, const int* in_sizes, int n_in,
                              void* d_out, int out_size, void* d_ws, size_t ws_size,
                              hipStream_t stream) {
  const float* x = (const float*)d_in[0];
  const float* Wqkv = (const float*)d_in[1];
  const float* bqkv = (const float*)d_in[2];
  const float* Wproj = (const float*)d_in[3];
  const float* bproj = (const float*)d_in[4];
  float* out = (float*)d_out;

  char* ws = (char*)d_ws;
  const size_t SZ_X = (size_t)NB * NS * ND * 2;
  const size_t SZ_WQKV = (size_t)ND * 3 * ND * 2;
  const size_t SZ_WPROJ = (size_t)ND * ND * 2;
  const size_t SZ_HEAD = (size_t)NB * NH * NS * HD;  // elements

  unsigned short* xbf = (unsigned short*)(ws);
  unsigned short* wqkvT = (unsigned short*)(ws + SZ_X);
  unsigned short* wprojT = (unsigned short*)(ws + SZ_X + SZ_WQKV);
  unsigned short* qw = (unsigned short*)(ws + SZ_X + SZ_WQKV + SZ_WPROJ);
  unsigned short* kw = qw + SZ_HEAD;
  unsigned short* vt = kw + SZ_HEAD;   // V stored transposed [bh][d][s] by qkv_gemm
  unsigned short* attn = vt + SZ_HEAD;

  (void)in_sizes; (void)n_in; (void)out_size; (void)ws_size;

  cvt_f32_bf16<<<(NB * NS * ND) / 1024, 256, 0, stream>>>(x, xbf);
  transpose_cvt<<<dim3(3 * ND / 32, ND / 32), 256, 0, stream>>>(Wqkv, wqkvT, ND, 3 * ND);
  transpose_cvt<<<dim3(ND / 32, ND / 32), 256, 0, stream>>>(Wproj, wprojT, ND, ND);

  qkv_gemm<<<1152, 256, 0, stream>>>(xbf, wqkvT, bqkv, qw, kw, vt);

  attn_kernel<<<384, 512, 0, stream>>>(qw, kw, vt, attn);

  proj_gemm<<<384, 256, 0, stream>>>(attn, wprojT, bproj, out);
}

// Round 17
// 122.288 us; speedup vs baseline: 1.0044x; 1.0044x over previous
//
#include <hip/hip_runtime.h>
#include <cstddef>

typedef float f32x4 __attribute__((ext_vector_type(4)));
typedef short s16x4 __attribute__((ext_vector_type(4)));
typedef short s16x8 __attribute__((ext_vector_type(8)));
typedef __bf16 bf16x8 __attribute__((ext_vector_type(8)));

#define NB 8
#define NS 1024
#define ND 768
#define NH 12
#define HD 64

__device__ __forceinline__ unsigned short f2bf(float f) {
  unsigned u = __builtin_bit_cast(unsigned, f);
  u += 0x7fffu + ((u >> 16) & 1u);
  return (unsigned short)(u >> 16);
}

__device__ __forceinline__ f32x4 mfma16(bf16x8 a, bf16x8 b, f32x4 c) {
  return __builtin_amdgcn_mfma_f32_16x16x32_bf16(a, b, c, 0, 0, 0);
}

__device__ __forceinline__ bf16x8 ld8(const unsigned short* p) {
  return *reinterpret_cast<const bf16x8*>(p);
}

__device__ __forceinline__ void gload16(unsigned short* lds_dst, const unsigned short* gsrc) {
  __builtin_amdgcn_global_load_lds(
      (const __attribute__((address_space(1))) unsigned int*)gsrc,
      (__attribute__((address_space(3))) unsigned int*)lds_dst, 16, 0, 0);
}

#define VMW(N) asm volatile("s_waitcnt vmcnt(" #N ")" ::: "memory")

// ---------------- pack kernels ----------------

__global__ __launch_bounds__(256) void cvt_f32_bf16(const float* __restrict__ in,
                                                    unsigned short* __restrict__ out) {
  int i = (blockIdx.x * 256 + threadIdx.x) * 4;
  float4 v = *reinterpret_cast<const float4*>(in + i);
  ushort4 o;
  o.x = f2bf(v.x); o.y = f2bf(v.y); o.z = f2bf(v.z); o.w = f2bf(v.w);
  *reinterpret_cast<ushort4*>(out + i) = o;
}

__global__ __launch_bounds__(256) void transpose_cvt(const float* __restrict__ in,
                                                     unsigned short* __restrict__ out,
                                                     int R, int C) {
  __shared__ float tile[32][33];
  int c0 = blockIdx.x * 32, r0 = blockIdx.y * 32;
  int tx = threadIdx.x & 31, ty = threadIdx.x >> 5;
#pragma unroll
  for (int i = 0; i < 32; i += 8)
    tile[ty + i][tx] = in[(size_t)(r0 + ty + i) * C + c0 + tx];
  __syncthreads();
#pragma unroll
  for (int i = 0; i < 32; i += 8)
    out[(size_t)(c0 + ty + i) * R + r0 + tx] = f2bf(tile[tx][ty + i]);
}

// ---------------- GEMM mainloops (verified disciplines) ----------------

#define SLOT 8192  // shorts per slot: A[128][32] + B[128][32]

// depth-3, 4-slot (r11/r13-verified: qkv 58us, FETCH/WRITE at ideal)
__device__ __forceinline__ void gemm_mainloop4(const unsigned short* __restrict__ A,
                                               const unsigned short* __restrict__ Bt,
                                               int K, int m0, int n0,
                                               unsigned short* smem,
                                               f32x4 (&acc)[4][4]) {
  int tid = threadIdx.x, lane = tid & 63, wid = tid >> 6;
  int wr = wid >> 1, wc = wid & 1;
  int ll = lane & 15, lh = lane >> 4;
  int swsrc = ((lane & 3) ^ ((lane >> 3) & 3)) * 8;

  const unsigned short* asrc = A + (size_t)(m0 + wid * 32 + (lane >> 2)) * K + swsrc;
  const unsigned short* bsrc = Bt + (size_t)(n0 + wid * 32 + (lane >> 2)) * K + swsrc;
  const int sw = (lh ^ ((ll >> 1) & 3)) * 8;
  const int nt = K / 32;  // 24

  auto stage = [&](int slot, int t) {
    unsigned short* ad = smem + slot * SLOT + wid * 1024;
    unsigned short* bd = smem + slot * SLOT + 4096 + wid * 1024;
    const unsigned short* as = asrc + t * 32;
    const unsigned short* bs = bsrc + t * 32;
    gload16(ad, as);
    gload16(ad + 512, as + (size_t)16 * K);
    gload16(bd, bs);
    gload16(bd + 512, bs + (size_t)16 * K);
  };

  stage(0, 0);
  stage(1, 1);
  stage(2, 2);
  VMW(8);
  __builtin_amdgcn_s_barrier();
  asm volatile("" ::: "memory");

  for (int t = 0; t < nt; ++t) {
    if (t + 3 < nt) stage((t + 3) & 3, t + 3);

    const unsigned short* Ab = smem + (t & 3) * SLOT;
    const unsigned short* Bb = Ab + 4096;

    __builtin_amdgcn_s_setprio(1);
    bf16x8 af[4], bg[4];
#pragma unroll
    for (int m = 0; m < 4; m++) af[m] = ld8(Ab + (wr * 64 + m * 16 + ll) * 32 + sw);
#pragma unroll
    for (int n = 0; n < 4; n++) bg[n] = ld8(Bb + (wc * 64 + n * 16 + ll) * 32 + sw);
#pragma unroll
    for (int m = 0; m < 4; m++)
#pragma unroll
      for (int n = 0; n < 4; n++) acc[m][n] = mfma16(af[m], bg[n], acc[m][n]);
    __builtin_amdgcn_s_setprio(0);

    if (t + 3 < nt) {
      VMW(8);
      __builtin_amdgcn_s_barrier();
      asm volatile("" ::: "memory");
    } else if (t + 2 < nt) {
      VMW(4);
      __builtin_amdgcn_s_barrier();
      asm volatile("" ::: "memory");
    } else if (t + 1 < nt) {
      VMW(0);
      __builtin_amdgcn_s_barrier();
      asm volatile("" ::: "memory");
    }
  }
}

// depth-2, 3-slot (r10-verified)
__device__ __forceinline__ void gemm_mainloop3(const unsigned short* __restrict__ A,
                                               const unsigned short* __restrict__ Bt,
                                               int K, int m0, int n0,
                                               unsigned short* smem,
                                               f32x4 (&acc)[4][4]) {
  int tid = threadIdx.x, lane = tid & 63, wid = tid >> 6;
  int wr = wid >> 1, wc = wid & 1;
  int ll = lane & 15, lh = lane >> 4;
  int swsrc = ((lane & 3) ^ ((lane >> 3) & 3)) * 8;

  const unsigned short* asrc = A + (size_t)(m0 + wid * 32 + (lane >> 2)) * K + swsrc;
  const unsigned short* bsrc = Bt + (size_t)(n0 + wid * 32 + (lane >> 2)) * K + swsrc;
  const int sw = (lh ^ ((ll >> 1) & 3)) * 8;
  const int nt = K / 32;

  auto stage = [&](int slot, int t) {
    unsigned short* ad = smem + slot * SLOT + wid * 1024;
    unsigned short* bd = smem + slot * SLOT + 4096 + wid * 1024;
    const unsigned short* as = asrc + t * 32;
    const unsigned short* bs = bsrc + t * 32;
    gload16(ad, as);
    gload16(ad + 512, as + (size_t)16 * K);
    gload16(bd, bs);
    gload16(bd + 512, bs + (size_t)16 * K);
  };

  stage(0, 0);
  stage(1, 1);
  VMW(4);
  __builtin_amdgcn_s_barrier();
  asm volatile("" ::: "memory");

  int slot = 0;
  for (int t = 0; t < nt; ++t) {
    if (t + 2 < nt) {
      int s2 = slot + 2; if (s2 >= 3) s2 -= 3;
      stage(s2, t + 2);
    }
    const unsigned short* Ab = smem + slot * SLOT;
    const unsigned short* Bb = Ab + 4096;

    __builtin_amdgcn_s_setprio(1);
    bf16x8 af[4], bg[4];
#pragma unroll
    for (int m = 0; m < 4; m++) af[m] = ld8(Ab + (wr * 64 + m * 16 + ll) * 32 + sw);
#pragma unroll
    for (int n = 0; n < 4; n++) bg[n] = ld8(Bb + (wc * 64 + n * 16 + ll) * 32 + sw);
#pragma unroll
    for (int m = 0; m < 4; m++)
#pragma unroll
      for (int n = 0; n < 4; n++) acc[m][n] = mfma16(af[m], bg[n], acc[m][n]);
    __builtin_amdgcn_s_setprio(0);

    if (t + 2 < nt) {
      VMW(4);
      __builtin_amdgcn_s_barrier();
      asm volatile("" ::: "memory");
    } else if (t + 2 == nt) {
      VMW(0);
      __builtin_amdgcn_s_barrier();
      asm volatile("" ::: "memory");
    }
    slot++; if (slot == 3) slot = 0;
  }
}

// ---------------- QKV GEMM (fused V-transpose epilogue; q pre-scaled into log2 domain) ----------------

#define QSCALE 0.18033688f  // 0.125 * log2(e): softmax then uses exp2 directly

__global__ __launch_bounds__(256, 2) void qkv_gemm(const unsigned short* __restrict__ xbf,
                                                   const unsigned short* __restrict__ WT,
                                                   const float* __restrict__ bias,
                                                   unsigned short* __restrict__ qw,
                                                   unsigned short* __restrict__ kw,
                                                   unsigned short* __restrict__ vt) {
  __shared__ __align__(16) unsigned short smem[4 * SLOT];
  int bid = blockIdx.x;
  int k8 = bid & 7, j = bid >> 3;
  int m0 = (k8 * 8 + (j & 7)) * 128;
  int n0 = (j >> 3) * 128;
  f32x4 acc[4][4];
#pragma unroll
  for (int m = 0; m < 4; m++)
#pragma unroll
    for (int n = 0; n < 4; n++) acc[m][n] = (f32x4){0.f, 0.f, 0.f, 0.f};

  gemm_mainloop4(xbf, WT, ND, m0, n0, smem, acc);

  int tid = threadIdx.x, lane = tid & 63, wid = tid >> 6;
  int wr = wid >> 1, wc = wid & 1;
  int ll = lane & 15, lh = lane >> 4;
  int which = n0 / ND;  // block-uniform

  if (which == 2) {
#pragma unroll
    for (int nf = 0; nf < 4; nf++) {
      int col = n0 + wc * 64 + nf * 16 + ll;
      float bv = bias[col];
      int w2 = col - 2 * ND;
      int h = w2 >> 6, d = w2 & 63;
#pragma unroll
      for (int mf = 0; mf < 4; mf++) {
        int m = m0 + wr * 64 + mf * 16 + lh * 4;
        int b = m >> 10, s = m & 1023;
        s16x4 pk;
        pk[0] = (short)f2bf(acc[mf][nf][0] + bv);
        pk[1] = (short)f2bf(acc[mf][nf][1] + bv);
        pk[2] = (short)f2bf(acc[mf][nf][2] + bv);
        pk[3] = (short)f2bf(acc[mf][nf][3] + bv);
        size_t idx = (((size_t)b * NH + h) * HD + d) * NS + s;
        *(s16x4*)&vt[idx] = pk;
      }
    }
  } else {
#pragma unroll
    for (int nf = 0; nf < 4; nf++) {
      int col = n0 + wc * 64 + nf * 16 + ll;
      float bv = bias[col];
      int w2 = col - which * ND;
      int h = w2 >> 6, d = w2 & 63;
#pragma unroll
      for (int mf = 0; mf < 4; mf++) {
#pragma unroll
        for (int r = 0; r < 4; r++) {
          int m = m0 + wr * 64 + mf * 16 + lh * 4 + r;
          int b = m >> 10, s = m & 1023;
          float v = acc[mf][nf][r] + bv;
          size_t idx = (((size_t)b * NH + h) * NS + s) * HD + d;
          if (which == 0)
            qw[idx] = f2bf(v * QSCALE);
          else
            kw[idx] = f2bf(v);
        }
      }
    }
  }
}

// ---------------- proj GEMM ----------------

__global__ __launch_bounds__(256, 3) void proj_gemm(const unsigned short* __restrict__ abf,
                                                    const unsigned short* __restrict__ WT,
                                                    const float* __restrict__ bias,
                                                    float* __restrict__ out) {
  __shared__ __align__(16) unsigned short smem[3 * SLOT];
  int bid = blockIdx.x;
  int k8 = bid & 7, j = bid >> 3;
  int m0 = (k8 * 8 + (j & 7)) * 128;
  int n0 = (j >> 3) * 128;
  f32x4 acc[4][4];
#pragma unroll
  for (int m = 0; m < 4; m++)
#pragma unroll
    for (int n = 0; n < 4; n++) acc[m][n] = (f32x4){0.f, 0.f, 0.f, 0.f};

  gemm_mainloop3(abf, WT, ND, m0, n0, smem, acc);

  int tid = threadIdx.x, lane = tid & 63, wid = tid >> 6;
  int wr = wid >> 1, wc = wid & 1;
  int ll = lane & 15, lh = lane >> 4;
#pragma unroll
  for (int nf = 0; nf < 4; nf++) {
    int col = n0 + wc * 64 + nf * 16 + ll;
    float bv = bias[col];
#pragma unroll
    for (int mf = 0; mf < 4; mf++) {
#pragma unroll
      for (int r = 0; r < 4; r++) {
        int m = m0 + wr * 64 + mf * 16 + lh * 4 + r;
        out[(size_t)m * ND + col] = acc[mf][nf][r] + bv;
      }
    }
  }
}

// ---------------- flash attention: paired-qt load balance (2 groups/wave, complementary tiles) ----------------
// Grid 384 = 8 XCD x 12 heads x 4 pairs. Pair p handles qtA=4+p and qtB=3-p:
// per-block work = 2(qtA+1)+2(qtB+1) = 18 tile-units, CONSTANT across all blocks
// (r13: imbalanced 2..16, critical CU ~21; r16: critical block 32 -> regressed).
// All 384 blocks co-resident (2/CU) -> zero tail. Staged tiles/head 72 -> 52.
// Group B shares group A's staged tiles (j-range is a prefix). Machinery
// (2-group state, shared Ps, per-group wave-uniform skip) verified in r16.

#define LP 88          // Ps row stride (shorts)
#define KVSLOT 8192    // shorts: K[64][64] + V[64][64]

__global__ __launch_bounds__(512) void attn_kernel(const unsigned short* __restrict__ qw,
                                                   const unsigned short* __restrict__ kw,
                                                   const unsigned short* __restrict__ vt,
                                                   unsigned short* __restrict__ attn_out) {
  int bid = blockIdx.x;
  int xcd = bid & 7, j = bid >> 3;        // j in [0,48)
  int grp = xcd * 12 + (j % 12);          // bh group: 12 heads per XCD
  int p = j / 12;                         // pair index 0..3
  int qtA = 4 + p, qtB = 3 - p;           // complementary q-tiles
  int b = grp / NH, h = grp % NH;
  __shared__ __align__(16) unsigned short KV[3 * KVSLOT];
  __shared__ __align__(16) unsigned short Ps[8][16 * LP];

  int tid = threadIdx.x, lane = tid & 63, wid = tid >> 6;
  int ll = lane & 15, lh = lane >> 4, r7x = ll & 7;
  const size_t bhk = ((size_t)b * NH + h) * NS * HD;
  const size_t bhv = ((size_t)b * NH + h) * HD * NS;

  int q0w[2] = {qtA * 128 + wid * 16, qtB * 128 + wid * 16};

  bf16x8 qf[2][2];
#pragma unroll
  for (int g = 0; g < 2; g++) {
    qf[g][0] = ld8(&qw[bhk + (size_t)(q0w[g] + ll) * HD + lh * 8]);
    qf[g][1] = ld8(&qw[bhk + (size_t)(q0w[g] + ll) * HD + 32 + lh * 8]);
  }

  f32x4 o[2][4];
#pragma unroll
  for (int g = 0; g < 2; g++)
#pragma unroll
    for (int n = 0; n < 4; n++) o[g][n] = (f32x4){0.f, 0.f, 0.f, 0.f};
  float m_r[2] = {-1e30f, -1e30f}, l_r[2] = {0.f, 0.f};

  int srow = tid >> 3;
  int scol = ((tid & 7) ^ ((tid >> 3) & 7)) * 8;
  const unsigned short* ksrc = kw + bhk + (size_t)srow * HD + scol;
  const unsigned short* vsrc = vt + bhv + (size_t)srow * NS + scol;

  unsigned short* pw = &Ps[wid][ll * LP];
  const int nt = 2 * (qtA + 1);  // longer range (>= 10)

  auto stage = [&](int slot, int t) {
    unsigned short* kd = KV + slot * KVSLOT + wid * 512;
    unsigned short* vd = KV + slot * KVSLOT + 4096 + wid * 512;
    gload16(kd, ksrc + (size_t)t * 64 * HD);
    gload16(vd, vsrc + t * 64);
  };

  stage(0, 0);
  stage(1, 1);
  VMW(2);
  __builtin_amdgcn_s_barrier();
  asm volatile("" ::: "memory");

  int slot = 0;
  for (int t = 0; t < nt; ++t) {
    if (t + 2 < nt) {
      int s2 = slot + 2; if (s2 >= 3) s2 -= 3;
      stage(s2, t + 2);
    }
    int j0 = t * 64;
    const unsigned short* Kb = KV + slot * KVSLOT;
    const unsigned short* Vb = Kb + 4096;

#pragma unroll
    for (int g = 0; g < 2; g++) {
      if (j0 <= q0w[g] + 15) {  // wave-uniform per-group causal skip
        f32x4 sa[4];
#pragma unroll
        for (int n = 0; n < 4; n++) {
          bf16x8 kf0 = ld8(Kb + (n * 16 + ll) * 64 + (lh ^ r7x) * 8);
          bf16x8 kf1 = ld8(Kb + (n * 16 + ll) * 64 + ((4 + lh) ^ r7x) * 8);
          sa[n] = mfma16(kf0, qf[g][0], (f32x4){0.f, 0.f, 0.f, 0.f});
          sa[n] = mfma16(kf1, qf[g][1], sa[n]);
        }

        if (j0 + 63 > q0w[g]) {  // diagonal tile: causal mask
          int qme = q0w[g] + ll;
#pragma unroll
          for (int n = 0; n < 4; n++)
#pragma unroll
            for (int r = 0; r < 4; r++)
              if (j0 + n * 16 + lh * 4 + r > qme) sa[n][r] = -1e30f;
        }

        float t0 = fmaxf(fmaxf(sa[0][0], sa[0][1]), fmaxf(sa[0][2], sa[0][3]));
        float t1 = fmaxf(fmaxf(sa[1][0], sa[1][1]), fmaxf(sa[1][2], sa[1][3]));
        float t2 = fmaxf(fmaxf(sa[2][0], sa[2][1]), fmaxf(sa[2][2], sa[2][3]));
        float t3 = fmaxf(fmaxf(sa[3][0], sa[3][1]), fmaxf(sa[3][2], sa[3][3]));
        float tmax = fmaxf(fmaxf(t0, t1), fmaxf(t2, t3));
        tmax = fmaxf(tmax, __shfl_xor(tmax, 16));
        tmax = fmaxf(tmax, __shfl_xor(tmax, 32));

        // defer-max (log2 domain): skip rescale while growth <= 11.5
        if (!__all(tmax - m_r[g] <= 11.5f)) {
          float mnew = fmaxf(m_r[g], tmax);
          float alpha = exp2f(m_r[g] - mnew);
          m_r[g] = mnew;
          l_r[g] *= alpha;
          float ab0 = __shfl(alpha, lh * 4 + 0);
          float ab1 = __shfl(alpha, lh * 4 + 1);
          float ab2 = __shfl(alpha, lh * 4 + 2);
          float ab3 = __shfl(alpha, lh * 4 + 3);
#pragma unroll
          for (int n2 = 0; n2 < 4; n2++) {
            o[g][n2][0] *= ab0; o[g][n2][1] *= ab1;
            o[g][n2][2] *= ab2; o[g][n2][3] *= ab3;
          }
        }

        float pv[4][4];
        float ssum = 0.f;
#pragma unroll
        for (int n = 0; n < 4; n++)
#pragma unroll
          for (int r = 0; r < 4; r++) {
            pv[n][r] = exp2f(sa[n][r] - m_r[g]);
            ssum += pv[n][r];
          }
        ssum += __shfl_xor(ssum, 16);
        ssum += __shfl_xor(ssum, 32);
        l_r[g] += ssum;

#pragma unroll
        for (int n = 0; n < 4; n++) {
          s16x4 pk;
          pk[0] = (short)f2bf(pv[n][0]);
          pk[1] = (short)f2bf(pv[n][1]);
          pk[2] = (short)f2bf(pv[n][2]);
          pk[3] = (short)f2bf(pv[n][3]);
          *(s16x4*)&pw[n * 16 + lh * 4] = pk;
        }

#pragma unroll
        for (int c = 0; c < 2; c++) {
          bf16x8 pf = ld8(&pw[c * 32 + lh * 8]);
#pragma unroll
          for (int n2 = 0; n2 < 4; n2++) {
            bf16x8 vf = ld8(Vb + (n2 * 16 + ll) * 64 + ((c * 4 + lh) ^ r7x) * 8);
            o[g][n2] = mfma16(pf, vf, o[g][n2]);
          }
        }
      }
    }

    if (t + 2 < nt) {
      VMW(2);
      __builtin_amdgcn_s_barrier();
      asm volatile("" ::: "memory");
    } else if (t + 2 == nt) {
      VMW(0);
      __builtin_amdgcn_s_barrier();
      asm volatile("" ::: "memory");
    }
    slot++; if (slot == 3) slot = 0;
  }

  // epilogue: normalize + store merged heads [B,S,D]
#pragma unroll
  for (int g = 0; g < 2; g++) {
    float lrec = 1.0f / l_r[g];
    float lb0 = __shfl(lrec, lh * 4 + 0);
    float lb1 = __shfl(lrec, lh * 4 + 1);
    float lb2 = __shfl(lrec, lh * 4 + 2);
    float lb3 = __shfl(lrec, lh * 4 + 3);
#pragma unroll
    for (int n2 = 0; n2 < 4; n2++) {
      int d = n2 * 16 + ll;
      int qb = q0w[g] + lh * 4;
      attn_out[((size_t)b * NS + qb + 0) * ND + h * HD + d] = f2bf(o[g][n2][0] * lb0);
      attn_out[((size_t)b * NS + qb + 1) * ND + h * HD + d] = f2bf(o[g][n2][1] * lb1);
      attn_out[((size_t)b * NS + qb + 2) * ND + h * HD + d] = f2bf(o[g][n2][2] * lb2);
      attn_out[((size_t)b * NS + qb + 3) * ND + h * HD + d] = f2bf(o[g][n2][3] * lb3);
    }
  }
}

// ---------------- launch ----------------

extern "C" void kernel_launch(void* const* d_in, const int* in_sizes, int n_in,
                              void* d_out, int out_size, void* d_ws, size_t ws_size,
                              hipStream_t stream) {
  const float* x = (const float*)d_in[0];
  const float* Wqkv = (const float*)d_in[1];
  const float* bqkv = (const float*)d_in[2];
  const float* Wproj = (const float*)d_in[3];
  const float* bproj = (const float*)d_in[4];
  float* out = (float*)d_out;

  char* ws = (char*)d_ws;
  const size_t SZ_X = (size_t)NB * NS * ND * 2;
  const size_t SZ_WQKV = (size_t)ND * 3 * ND * 2;
  const size_t SZ_WPROJ = (size_t)ND * ND * 2;
  const size_t SZ_HEAD = (size_t)NB * NH * NS * HD;  // elements

  unsigned short* xbf = (unsigned short*)(ws);
  unsigned short* wqkvT = (unsigned short*)(ws + SZ_X);
  unsigned short* wprojT = (unsigned short*)(ws + SZ_X + SZ_WQKV);
  unsigned short* qw = (unsigned short*)(ws + SZ_X + SZ_WQKV + SZ_WPROJ);
  unsigned short* kw = qw + SZ_HEAD;
  unsigned short* vt = kw + SZ_HEAD;   // V stored transposed [bh][d][s] by qkv_gemm
  unsigned short* attn = vt + SZ_HEAD;

  (void)in_sizes; (void)n_in; (void)out_size; (void)ws_size;

  cvt_f32_bf16<<<(NB * NS * ND) / 1024, 256, 0, stream>>>(x, xbf);
  transpose_cvt<<<dim3(3 * ND / 32, ND / 32), 256, 0, stream>>>(Wqkv, wqkvT, ND, 3 * ND);
  transpose_cvt<<<dim3(ND / 32, ND / 32), 256, 0, stream>>>(Wproj, wprojT, ND, ND);

  qkv_gemm<<<1152, 256, 0, stream>>>(xbf, wqkvT, bqkv, qw, kw, vt);

  attn_kernel<<<384, 512, 0, stream>>>(qw, kw, vt, attn);

  proj_gemm<<<384, 256, 0, stream>>>(attn, wprojT, bproj, out);
}

// Round 18
// 115.182 us; speedup vs baseline: 1.0664x; 1.0617x over previous
//
#include <hip/hip_runtime.h>
#include <cstddef>

typedef float f32x4 __attribute__((ext_vector_type(4)));
typedef short s16x4 __attribute__((ext_vector_type(4)));
typedef short s16x8 __attribute__((ext_vector_type(8)));
typedef __bf16 bf16x8 __attribute__((ext_vector_type(8)));

#define NB 8
#define NS 1024
#define ND 768
#define NH 12
#define HD 64

__device__ __forceinline__ unsigned short f2bf(float f) {
  unsigned u = __builtin_bit_cast(unsigned, f);
  u += 0x7fffu + ((u >> 16) & 1u);
  return (unsigned short)(u >> 16);
}

__device__ __forceinline__ f32x4 mfma16(bf16x8 a, bf16x8 b, f32x4 c) {
  return __builtin_amdgcn_mfma_f32_16x16x32_bf16(a, b, c, 0, 0, 0);
}

__device__ __forceinline__ bf16x8 ld8(const unsigned short* p) {
  return *reinterpret_cast<const bf16x8*>(p);
}

__device__ __forceinline__ void gload16(unsigned short* lds_dst, const unsigned short* gsrc) {
  __builtin_amdgcn_global_load_lds(
      (const __attribute__((address_space(1))) unsigned int*)gsrc,
      (__attribute__((address_space(3))) unsigned int*)lds_dst, 16, 0, 0);
}

#define VMW(N) asm volatile("s_waitcnt vmcnt(" #N ")" ::: "memory")

// ---------------- pack kernels ----------------

__global__ __launch_bounds__(256) void cvt_f32_bf16(const float* __restrict__ in,
                                                    unsigned short* __restrict__ out) {
  int i = (blockIdx.x * 256 + threadIdx.x) * 4;
  float4 v = *reinterpret_cast<const float4*>(in + i);
  ushort4 o;
  o.x = f2bf(v.x); o.y = f2bf(v.y); o.z = f2bf(v.z); o.w = f2bf(v.w);
  *reinterpret_cast<ushort4*>(out + i) = o;
}

__global__ __launch_bounds__(256) void transpose_cvt(const float* __restrict__ in,
                                                     unsigned short* __restrict__ out,
                                                     int R, int C) {
  __shared__ float tile[32][33];
  int c0 = blockIdx.x * 32, r0 = blockIdx.y * 32;
  int tx = threadIdx.x & 31, ty = threadIdx.x >> 5;
#pragma unroll
  for (int i = 0; i < 32; i += 8)
    tile[ty + i][tx] = in[(size_t)(r0 + ty + i) * C + c0 + tx];
  __syncthreads();
#pragma unroll
  for (int i = 0; i < 32; i += 8)
    out[(size_t)(c0 + ty + i) * R + r0 + tx] = f2bf(tile[tx][ty + i]);
}

// ---------------- GEMM mainloops (verified disciplines) ----------------

#define SLOT 8192  // shorts per slot: A[128][32] + B[128][32]

// depth-3, 4-slot (r11/r13-verified: qkv 58us, FETCH/WRITE at ideal)
__device__ __forceinline__ void gemm_mainloop4(const unsigned short* __restrict__ A,
                                               const unsigned short* __restrict__ Bt,
                                               int K, int m0, int n0,
                                               unsigned short* smem,
                                               f32x4 (&acc)[4][4]) {
  int tid = threadIdx.x, lane = tid & 63, wid = tid >> 6;
  int wr = wid >> 1, wc = wid & 1;
  int ll = lane & 15, lh = lane >> 4;
  int swsrc = ((lane & 3) ^ ((lane >> 3) & 3)) * 8;

  const unsigned short* asrc = A + (size_t)(m0 + wid * 32 + (lane >> 2)) * K + swsrc;
  const unsigned short* bsrc = Bt + (size_t)(n0 + wid * 32 + (lane >> 2)) * K + swsrc;
  const int sw = (lh ^ ((ll >> 1) & 3)) * 8;
  const int nt = K / 32;  // 24

  auto stage = [&](int slot, int t) {
    unsigned short* ad = smem + slot * SLOT + wid * 1024;
    unsigned short* bd = smem + slot * SLOT + 4096 + wid * 1024;
    const unsigned short* as = asrc + t * 32;
    const unsigned short* bs = bsrc + t * 32;
    gload16(ad, as);
    gload16(ad + 512, as + (size_t)16 * K);
    gload16(bd, bs);
    gload16(bd + 512, bs + (size_t)16 * K);
  };

  stage(0, 0);
  stage(1, 1);
  stage(2, 2);
  VMW(8);
  __builtin_amdgcn_s_barrier();
  asm volatile("" ::: "memory");

  for (int t = 0; t < nt; ++t) {
    if (t + 3 < nt) stage((t + 3) & 3, t + 3);

    const unsigned short* Ab = smem + (t & 3) * SLOT;
    const unsigned short* Bb = Ab + 4096;

    __builtin_amdgcn_s_setprio(1);
    bf16x8 af[4], bg[4];
#pragma unroll
    for (int m = 0; m < 4; m++) af[m] = ld8(Ab + (wr * 64 + m * 16 + ll) * 32 + sw);
#pragma unroll
    for (int n = 0; n < 4; n++) bg[n] = ld8(Bb + (wc * 64 + n * 16 + ll) * 32 + sw);
#pragma unroll
    for (int m = 0; m < 4; m++)
#pragma unroll
      for (int n = 0; n < 4; n++) acc[m][n] = mfma16(af[m], bg[n], acc[m][n]);
    __builtin_amdgcn_s_setprio(0);

    if (t + 3 < nt) {
      VMW(8);
      __builtin_amdgcn_s_barrier();
      asm volatile("" ::: "memory");
    } else if (t + 2 < nt) {
      VMW(4);
      __builtin_amdgcn_s_barrier();
      asm volatile("" ::: "memory");
    } else if (t + 1 < nt) {
      VMW(0);
      __builtin_amdgcn_s_barrier();
      asm volatile("" ::: "memory");
    }
  }
}

// depth-2, 3-slot (r10-verified)
__device__ __forceinline__ void gemm_mainloop3(const unsigned short* __restrict__ A,
                                               const unsigned short* __restrict__ Bt,
                                               int K, int m0, int n0,
                                               unsigned short* smem,
                                               f32x4 (&acc)[4][4]) {
  int tid = threadIdx.x, lane = tid & 63, wid = tid >> 6;
  int wr = wid >> 1, wc = wid & 1;
  int ll = lane & 15, lh = lane >> 4;
  int swsrc = ((lane & 3) ^ ((lane >> 3) & 3)) * 8;

  const unsigned short* asrc = A + (size_t)(m0 + wid * 32 + (lane >> 2)) * K + swsrc;
  const unsigned short* bsrc = Bt + (size_t)(n0 + wid * 32 + (lane >> 2)) * K + swsrc;
  const int sw = (lh ^ ((ll >> 1) & 3)) * 8;
  const int nt = K / 32;

  auto stage = [&](int slot, int t) {
    unsigned short* ad = smem + slot * SLOT + wid * 1024;
    unsigned short* bd = smem + slot * SLOT + 4096 + wid * 1024;
    const unsigned short* as = asrc + t * 32;
    const unsigned short* bs = bsrc + t * 32;
    gload16(ad, as);
    gload16(ad + 512, as + (size_t)16 * K);
    gload16(bd, bs);
    gload16(bd + 512, bs + (size_t)16 * K);
  };

  stage(0, 0);
  stage(1, 1);
  VMW(4);
  __builtin_amdgcn_s_barrier();
  asm volatile("" ::: "memory");

  int slot = 0;
  for (int t = 0; t < nt; ++t) {
    if (t + 2 < nt) {
      int s2 = slot + 2; if (s2 >= 3) s2 -= 3;
      stage(s2, t + 2);
    }
    const unsigned short* Ab = smem + slot * SLOT;
    const unsigned short* Bb = Ab + 4096;

    __builtin_amdgcn_s_setprio(1);
    bf16x8 af[4], bg[4];
#pragma unroll
    for (int m = 0; m < 4; m++) af[m] = ld8(Ab + (wr * 64 + m * 16 + ll) * 32 + sw);
#pragma unroll
    for (int n = 0; n < 4; n++) bg[n] = ld8(Bb + (wc * 64 + n * 16 + ll) * 32 + sw);
#pragma unroll
    for (int m = 0; m < 4; m++)
#pragma unroll
      for (int n = 0; n < 4; n++) acc[m][n] = mfma16(af[m], bg[n], acc[m][n]);
    __builtin_amdgcn_s_setprio(0);

    if (t + 2 < nt) {
      VMW(4);
      __builtin_amdgcn_s_barrier();
      asm volatile("" ::: "memory");
    } else if (t + 2 == nt) {
      VMW(0);
      __builtin_amdgcn_s_barrier();
      asm volatile("" ::: "memory");
    }
    slot++; if (slot == 3) slot = 0;
  }
}

// ---------------- QKV GEMM (fused V-transpose epilogue; q pre-scaled into log2 domain) ----------------

#define QSCALE 0.18033688f  // 0.125 * log2(e): softmax then uses exp2 directly

__global__ __launch_bounds__(256, 2) void qkv_gemm(const unsigned short* __restrict__ xbf,
                                                   const unsigned short* __restrict__ WT,
                                                   const float* __restrict__ bias,
                                                   unsigned short* __restrict__ qw,
                                                   unsigned short* __restrict__ kw,
                                                   unsigned short* __restrict__ vt) {
  __shared__ __align__(16) unsigned short smem[4 * SLOT];
  int bid = blockIdx.x;
  int k8 = bid & 7, j = bid >> 3;
  int m0 = (k8 * 8 + (j & 7)) * 128;
  int n0 = (j >> 3) * 128;
  f32x4 acc[4][4];
#pragma unroll
  for (int m = 0; m < 4; m++)
#pragma unroll
    for (int n = 0; n < 4; n++) acc[m][n] = (f32x4){0.f, 0.f, 0.f, 0.f};

  gemm_mainloop4(xbf, WT, ND, m0, n0, smem, acc);

  int tid = threadIdx.x, lane = tid & 63, wid = tid >> 6;
  int wr = wid >> 1, wc = wid & 1;
  int ll = lane & 15, lh = lane >> 4;
  int which = n0 / ND;  // block-uniform

  if (which == 2) {
#pragma unroll
    for (int nf = 0; nf < 4; nf++) {
      int col = n0 + wc * 64 + nf * 16 + ll;
      float bv = bias[col];
      int w2 = col - 2 * ND;
      int h = w2 >> 6, d = w2 & 63;
#pragma unroll
      for (int mf = 0; mf < 4; mf++) {
        int m = m0 + wr * 64 + mf * 16 + lh * 4;
        int b = m >> 10, s = m & 1023;
        s16x4 pk;
        pk[0] = (short)f2bf(acc[mf][nf][0] + bv);
        pk[1] = (short)f2bf(acc[mf][nf][1] + bv);
        pk[2] = (short)f2bf(acc[mf][nf][2] + bv);
        pk[3] = (short)f2bf(acc[mf][nf][3] + bv);
        size_t idx = (((size_t)b * NH + h) * HD + d) * NS + s;
        *(s16x4*)&vt[idx] = pk;
      }
    }
  } else {
#pragma unroll
    for (int nf = 0; nf < 4; nf++) {
      int col = n0 + wc * 64 + nf * 16 + ll;
      float bv = bias[col];
      int w2 = col - which * ND;
      int h = w2 >> 6, d = w2 & 63;
#pragma unroll
      for (int mf = 0; mf < 4; mf++) {
#pragma unroll
        for (int r = 0; r < 4; r++) {
          int m = m0 + wr * 64 + mf * 16 + lh * 4 + r;
          int b = m >> 10, s = m & 1023;
          float v = acc[mf][nf][r] + bv;
          size_t idx = (((size_t)b * NH + h) * NS + s) * HD + d;
          if (which == 0)
            qw[idx] = f2bf(v * QSCALE);
          else
            kw[idx] = f2bf(v);
        }
      }
    }
  }
}

// ---------------- proj GEMM ----------------

__global__ __launch_bounds__(256, 3) void proj_gemm(const unsigned short* __restrict__ abf,
                                                    const unsigned short* __restrict__ WT,
                                                    const float* __restrict__ bias,
                                                    float* __restrict__ out) {
  __shared__ __align__(16) unsigned short smem[3 * SLOT];
  int bid = blockIdx.x;
  int k8 = bid & 7, j = bid >> 3;
  int m0 = (k8 * 8 + (j & 7)) * 128;
  int n0 = (j >> 3) * 128;
  f32x4 acc[4][4];
#pragma unroll
  for (int m = 0; m < 4; m++)
#pragma unroll
    for (int n = 0; n < 4; n++) acc[m][n] = (f32x4){0.f, 0.f, 0.f, 0.f};

  gemm_mainloop3(abf, WT, ND, m0, n0, smem, acc);

  int tid = threadIdx.x, lane = tid & 63, wid = tid >> 6;
  int wr = wid >> 1, wc = wid & 1;
  int ll = lane & 15, lh = lane >> 4;
#pragma unroll
  for (int nf = 0; nf < 4; nf++) {
    int col = n0 + wc * 64 + nf * 16 + ll;
    float bv = bias[col];
#pragma unroll
    for (int mf = 0; mf < 4; mf++) {
#pragma unroll
      for (int r = 0; r < 4; r++) {
        int m = m0 + wr * 64 + mf * 16 + lh * 4 + r;
        out[(size_t)m * ND + col] = acc[mf][nf][r] + bv;
      }
    }
  }
}

// ---------------- flash attention (r13-verified: XCD-grouped, log2 softmax) ----------------

#define LP 88          // Ps row stride (shorts)
#define KVSLOT 8192    // shorts: K[64][64] + V[64][64]

__global__ __launch_bounds__(512) void attn_kernel(const unsigned short* __restrict__ qw,
                                                   const unsigned short* __restrict__ kw,
                                                   const unsigned short* __restrict__ vt,
                                                   unsigned short* __restrict__ attn_out) {
  int bid = blockIdx.x;
  int xcd = bid & 7, j = bid >> 3;        // j in [0,96)
  int grp = xcd * 12 + (j % 12);          // bh group: 12 heads per XCD
  int qt = 7 - (j / 12);                  // heavy q-tiles first
  int b = grp / NH, h = grp % NH;
  __shared__ __align__(16) unsigned short KV[3 * KVSLOT];
  __shared__ __align__(16) unsigned short Ps[8][16 * LP];

  int tid = threadIdx.x, lane = tid & 63, wid = tid >> 6;
  int ll = lane & 15, lh = lane >> 4, r7x = ll & 7;
  int q0 = qt * 128, q0w = q0 + wid * 16;
  const size_t bhk = ((size_t)b * NH + h) * NS * HD;
  const size_t bhv = ((size_t)b * NH + h) * HD * NS;

  bf16x8 qf0 = ld8(&qw[bhk + (size_t)(q0w + ll) * HD + lh * 8]);
  bf16x8 qf1 = ld8(&qw[bhk + (size_t)(q0w + ll) * HD + 32 + lh * 8]);

  f32x4 o[4];
#pragma unroll
  for (int n = 0; n < 4; n++) o[n] = (f32x4){0.f, 0.f, 0.f, 0.f};
  float m_r = -1e30f, l_r = 0.f;

  int srow = tid >> 3;
  int scol = ((tid & 7) ^ ((tid >> 3) & 7)) * 8;
  const unsigned short* ksrc = kw + bhk + (size_t)srow * HD + scol;
  const unsigned short* vsrc = vt + bhv + (size_t)srow * NS + scol;

  unsigned short* pw = &Ps[wid][ll * LP];
  const int qme = q0w + ll;
  const int qmaxw = q0w + 15;
  const int nt = 2 * (qt + 1);

  auto stage = [&](int slot, int t) {
    unsigned short* kd = KV + slot * KVSLOT + wid * 512;
    unsigned short* vd = KV + slot * KVSLOT + 4096 + wid * 512;
    gload16(kd, ksrc + (size_t)t * 64 * HD);
    gload16(vd, vsrc + t * 64);
  };

  stage(0, 0);
  stage(1, 1);
  VMW(2);
  __builtin_amdgcn_s_barrier();
  asm volatile("" ::: "memory");

  int slot = 0;
  for (int t = 0; t < nt; ++t) {
    if (t + 2 < nt) {
      int s2 = slot + 2; if (s2 >= 3) s2 -= 3;
      stage(s2, t + 2);
    }
    int j0 = t * 64;

    if (j0 <= qmaxw) {
      const unsigned short* Kb = KV + slot * KVSLOT;
      const unsigned short* Vb = Kb + 4096;

      f32x4 sa[4];
#pragma unroll
      for (int n = 0; n < 4; n++) {
        bf16x8 kf0 = ld8(Kb + (n * 16 + ll) * 64 + (lh ^ r7x) * 8);
        bf16x8 kf1 = ld8(Kb + (n * 16 + ll) * 64 + ((4 + lh) ^ r7x) * 8);
        sa[n] = mfma16(kf0, qf0, (f32x4){0.f, 0.f, 0.f, 0.f});
        sa[n] = mfma16(kf1, qf1, sa[n]);
      }

      if (j0 + 63 > q0w) {
#pragma unroll
        for (int n = 0; n < 4; n++)
#pragma unroll
          for (int r = 0; r < 4; r++)
            if (j0 + n * 16 + lh * 4 + r > qme) sa[n][r] = -1e30f;
      }

      float t0 = fmaxf(fmaxf(sa[0][0], sa[0][1]), fmaxf(sa[0][2], sa[0][3]));
      float t1 = fmaxf(fmaxf(sa[1][0], sa[1][1]), fmaxf(sa[1][2], sa[1][3]));
      float t2 = fmaxf(fmaxf(sa[2][0], sa[2][1]), fmaxf(sa[2][2], sa[2][3]));
      float t3 = fmaxf(fmaxf(sa[3][0], sa[3][1]), fmaxf(sa[3][2], sa[3][3]));
      float tmax = fmaxf(fmaxf(t0, t1), fmaxf(t2, t3));
      tmax = fmaxf(tmax, __shfl_xor(tmax, 16));
      tmax = fmaxf(tmax, __shfl_xor(tmax, 32));

      // defer-max (log2 domain): skip rescale while growth <= 11.5 (P <= 2^11.5)
      if (!__all(tmax - m_r <= 11.5f)) {
        float mnew = fmaxf(m_r, tmax);
        float alpha = exp2f(m_r - mnew);
        m_r = mnew;
        l_r *= alpha;
        float ab0 = __shfl(alpha, lh * 4 + 0);
        float ab1 = __shfl(alpha, lh * 4 + 1);
        float ab2 = __shfl(alpha, lh * 4 + 2);
        float ab3 = __shfl(alpha, lh * 4 + 3);
#pragma unroll
        for (int n2 = 0; n2 < 4; n2++) {
          o[n2][0] *= ab0; o[n2][1] *= ab1; o[n2][2] *= ab2; o[n2][3] *= ab3;
        }
      }

      float p[4][4];
      float ssum = 0.f;
#pragma unroll
      for (int n = 0; n < 4; n++)
#pragma unroll
        for (int r = 0; r < 4; r++) {
          p[n][r] = exp2f(sa[n][r] - m_r);
          ssum += p[n][r];
        }
      ssum += __shfl_xor(ssum, 16);
      ssum += __shfl_xor(ssum, 32);
      l_r += ssum;

#pragma unroll
      for (int n = 0; n < 4; n++) {
        s16x4 pk;
        pk[0] = (short)f2bf(p[n][0]);
        pk[1] = (short)f2bf(p[n][1]);
        pk[2] = (short)f2bf(p[n][2]);
        pk[3] = (short)f2bf(p[n][3]);
        *(s16x4*)&pw[n * 16 + lh * 4] = pk;
      }

#pragma unroll
      for (int c = 0; c < 2; c++) {
        bf16x8 pf = ld8(&pw[c * 32 + lh * 8]);
#pragma unroll
        for (int n2 = 0; n2 < 4; n2++) {
          bf16x8 vf = ld8(Vb + (n2 * 16 + ll) * 64 + ((c * 4 + lh) ^ r7x) * 8);
          o[n2] = mfma16(pf, vf, o[n2]);
        }
      }
    }

    if (t + 2 < nt) {
      VMW(2);
      __builtin_amdgcn_s_barrier();
      asm volatile("" ::: "memory");
    } else if (t + 2 == nt) {
      VMW(0);
      __builtin_amdgcn_s_barrier();
      asm volatile("" ::: "memory");
    }
    slot++; if (slot == 3) slot = 0;
  }

  float lrec = 1.0f / l_r;
  float lb0 = __shfl(lrec, lh * 4 + 0);
  float lb1 = __shfl(lrec, lh * 4 + 1);
  float lb2 = __shfl(lrec, lh * 4 + 2);
  float lb3 = __shfl(lrec, lh * 4 + 3);
#pragma unroll
  for (int n2 = 0; n2 < 4; n2++) {
    int d = n2 * 16 + ll;
    int qb = q0w + lh * 4;
    attn_out[((size_t)b * NS + qb + 0) * ND + h * HD + d] = f2bf(o[n2][0] * lb0);
    attn_out[((size_t)b * NS + qb + 1) * ND + h * HD + d] = f2bf(o[n2][1] * lb1);
    attn_out[((size_t)b * NS + qb + 2) * ND + h * HD + d] = f2bf(o[n2][2] * lb2);
    attn_out[((size_t)b * NS + qb + 3) * ND + h * HD + d] = f2bf(o[n2][3] * lb3);
  }
}

// ---------------- launch ----------------

extern "C" void kernel_launch(void* const* d_in, const int* in_sizes, int n_in,
                              void* d_out, int out_size, void* d_ws, size_t ws_size,
                              hipStream_t stream) {
  const float* x = (const float*)d_in[0];
  const float* Wqkv = (const float*)d_in[1];
  const float* bqkv = (const float*)d_in[2];
  const float* Wproj = (const float*)d_in[3];
  const float* bproj = (const float*)d_in[4];
  float* out = (float*)d_out;

  char* ws = (char*)d_ws;
  const size_t SZ_X = (size_t)NB * NS * ND * 2;
  const size_t SZ_WQKV = (size_t)ND * 3 * ND * 2;
  const size_t SZ_WPROJ = (size_t)ND * ND * 2;
  const size_t SZ_HEAD = (size_t)NB * NH * NS * HD;  // elements

  unsigned short* xbf = (unsigned short*)(ws);
  unsigned short* wqkvT = (unsigned short*)(ws + SZ_X);
  unsigned short* wprojT = (unsigned short*)(ws + SZ_X + SZ_WQKV);
  unsigned short* qw = (unsigned short*)(ws + SZ_X + SZ_WQKV + SZ_WPROJ);
  unsigned short* kw = qw + SZ_HEAD;
  unsigned short* vt = kw + SZ_HEAD;   // V stored transposed [bh][d][s] by qkv_gemm
  unsigned short* attn = vt + SZ_HEAD;

  (void)in_sizes; (void)n_in; (void)out_size; (void)ws_size;

  cvt_f32_bf16<<<(NB * NS * ND) / 1024, 256, 0, stream>>>(x, xbf);
  transpose_cvt<<<dim3(3 * ND / 32, ND / 32), 256, 0, stream>>>(Wqkv, wqkvT, ND, 3 * ND);
  transpose_cvt<<<dim3(ND / 32, ND / 32), 256, 0, stream>>>(Wproj, wprojT, ND, ND);

  qkv_gemm<<<1152, 256, 0, stream>>>(xbf, wqkvT, bqkv, qw, kw, vt);

  attn_kernel<<<768, 512, 0, stream>>>(qw, kw, vt, attn);

  proj_gemm<<<384, 256, 0, stream>>>(attn, wprojT, bproj, out);
}

// Round 19
// 113.815 us; speedup vs baseline: 1.0792x; 1.0120x over previous
//
#include <hip/hip_runtime.h>
#include <cstddef>

typedef float f32x4 __attribute__((ext_vector_type(4)));
typedef short s16x4 __attribute__((ext_vector_type(4)));
typedef short s16x8 __attribute__((ext_vector_type(8)));
typedef __bf16 bf16x8 __attribute__((ext_vector_type(8)));

#define NB 8
#define NS 1024
#define ND 768
#define NH 12
#define HD 64

__device__ __forceinline__ unsigned short f2bf(float f) {
  unsigned u = __builtin_bit_cast(unsigned, f);
  u += 0x7fffu + ((u >> 16) & 1u);
  return (unsigned short)(u >> 16);
}

__device__ __forceinline__ f32x4 mfma16(bf16x8 a, bf16x8 b, f32x4 c) {
  return __builtin_amdgcn_mfma_f32_16x16x32_bf16(a, b, c, 0, 0, 0);
}

__device__ __forceinline__ bf16x8 ld8(const unsigned short* p) {
  return *reinterpret_cast<const bf16x8*>(p);
}

__device__ __forceinline__ void gload16(unsigned short* lds_dst, const unsigned short* gsrc) {
  __builtin_amdgcn_global_load_lds(
      (const __attribute__((address_space(1))) unsigned int*)gsrc,
      (__attribute__((address_space(3))) unsigned int*)lds_dst, 16, 0, 0);
}

#define VMW(N) asm volatile("s_waitcnt vmcnt(" #N ")" ::: "memory")

// ---------------- pack kernels ----------------

__global__ __launch_bounds__(256) void cvt_f32_bf16(const float* __restrict__ in,
                                                    unsigned short* __restrict__ out) {
  int i = (blockIdx.x * 256 + threadIdx.x) * 4;
  float4 v = *reinterpret_cast<const float4*>(in + i);
  ushort4 o;
  o.x = f2bf(v.x); o.y = f2bf(v.y); o.z = f2bf(v.z); o.w = f2bf(v.w);
  *reinterpret_cast<ushort4*>(out + i) = o;
}

__global__ __launch_bounds__(256) void transpose_cvt(const float* __restrict__ in,
                                                     unsigned short* __restrict__ out,
                                                     int R, int C) {
  __shared__ float tile[32][33];
  int c0 = blockIdx.x * 32, r0 = blockIdx.y * 32;
  int tx = threadIdx.x & 31, ty = threadIdx.x >> 5;
#pragma unroll
  for (int i = 0; i < 32; i += 8)
    tile[ty + i][tx] = in[(size_t)(r0 + ty + i) * C + c0 + tx];
  __syncthreads();
#pragma unroll
  for (int i = 0; i < 32; i += 8)
    out[(size_t)(c0 + ty + i) * R + r0 + tx] = f2bf(tile[tx][ty + i]);
}

// ---------------- GEMM mainloop: depth-2, 3-slot, 128x128, BK=32 (r10/proj-verified) ----------------
// 48 KB LDS -> 3 blocks/CU. With col-major XCD mapping + ideal traffic (r13-measured),
// this is the most efficient config in the pipeline (proj: ~740 TF). r19 isolates the
// occupancy term on qkv (r10's 3-slot test predates col-major + fused-V epilogue).

#define SLOT 8192  // shorts per slot: A[128][32] + B[128][32]

__device__ __forceinline__ void gemm_mainloop3(const unsigned short* __restrict__ A,
                                               const unsigned short* __restrict__ Bt,
                                               int K, int m0, int n0,
                                               unsigned short* smem,
                                               f32x4 (&acc)[4][4]) {
  int tid = threadIdx.x, lane = tid & 63, wid = tid >> 6;
  int wr = wid >> 1, wc = wid & 1;
  int ll = lane & 15, lh = lane >> 4;
  int swsrc = ((lane & 3) ^ ((lane >> 3) & 3)) * 8;

  const unsigned short* asrc = A + (size_t)(m0 + wid * 32 + (lane >> 2)) * K + swsrc;
  const unsigned short* bsrc = Bt + (size_t)(n0 + wid * 32 + (lane >> 2)) * K + swsrc;
  const int sw = (lh ^ ((ll >> 1) & 3)) * 8;
  const int nt = K / 32;

  auto stage = [&](int slot, int t) {
    unsigned short* ad = smem + slot * SLOT + wid * 1024;
    unsigned short* bd = smem + slot * SLOT + 4096 + wid * 1024;
    const unsigned short* as = asrc + t * 32;
    const unsigned short* bs = bsrc + t * 32;
    gload16(ad, as);
    gload16(ad + 512, as + (size_t)16 * K);
    gload16(bd, bs);
    gload16(bd + 512, bs + (size_t)16 * K);
  };

  stage(0, 0);
  stage(1, 1);
  VMW(4);
  __builtin_amdgcn_s_barrier();
  asm volatile("" ::: "memory");

  int slot = 0;
  for (int t = 0; t < nt; ++t) {
    if (t + 2 < nt) {
      int s2 = slot + 2; if (s2 >= 3) s2 -= 3;
      stage(s2, t + 2);
    }
    const unsigned short* Ab = smem + slot * SLOT;
    const unsigned short* Bb = Ab + 4096;

    __builtin_amdgcn_s_setprio(1);
    bf16x8 af[4], bg[4];
#pragma unroll
    for (int m = 0; m < 4; m++) af[m] = ld8(Ab + (wr * 64 + m * 16 + ll) * 32 + sw);
#pragma unroll
    for (int n = 0; n < 4; n++) bg[n] = ld8(Bb + (wc * 64 + n * 16 + ll) * 32 + sw);
#pragma unroll
    for (int m = 0; m < 4; m++)
#pragma unroll
      for (int n = 0; n < 4; n++) acc[m][n] = mfma16(af[m], bg[n], acc[m][n]);
    __builtin_amdgcn_s_setprio(0);

    if (t + 2 < nt) {
      VMW(4);
      __builtin_amdgcn_s_barrier();
      asm volatile("" ::: "memory");
    } else if (t + 2 == nt) {
      VMW(0);
      __builtin_amdgcn_s_barrier();
      asm volatile("" ::: "memory");
    }
    slot++; if (slot == 3) slot = 0;
  }
}

// ---------------- QKV GEMM (3-slot, 3 blocks/CU; fused V-transpose epilogue; log2-scaled q) ----------------

#define QSCALE 0.18033688f  // 0.125 * log2(e): softmax then uses exp2 directly

__global__ __launch_bounds__(256, 3) void qkv_gemm(const unsigned short* __restrict__ xbf,
                                                   const unsigned short* __restrict__ WT,
                                                   const float* __restrict__ bias,
                                                   unsigned short* __restrict__ qw,
                                                   unsigned short* __restrict__ kw,
                                                   unsigned short* __restrict__ vt) {
  __shared__ __align__(16) unsigned short smem[3 * SLOT];
  int bid = blockIdx.x;
  int k8 = bid & 7, j = bid >> 3;
  int m0 = (k8 * 8 + (j & 7)) * 128;
  int n0 = (j >> 3) * 128;
  f32x4 acc[4][4];
#pragma unroll
  for (int m = 0; m < 4; m++)
#pragma unroll
    for (int n = 0; n < 4; n++) acc[m][n] = (f32x4){0.f, 0.f, 0.f, 0.f};

  gemm_mainloop3(xbf, WT, ND, m0, n0, smem, acc);

  int tid = threadIdx.x, lane = tid & 63, wid = tid >> 6;
  int wr = wid >> 1, wc = wid & 1;
  int ll = lane & 15, lh = lane >> 4;
  int which = n0 / ND;  // block-uniform

  if (which == 2) {
#pragma unroll
    for (int nf = 0; nf < 4; nf++) {
      int col = n0 + wc * 64 + nf * 16 + ll;
      float bv = bias[col];
      int w2 = col - 2 * ND;
      int h = w2 >> 6, d = w2 & 63;
#pragma unroll
      for (int mf = 0; mf < 4; mf++) {
        int m = m0 + wr * 64 + mf * 16 + lh * 4;
        int b = m >> 10, s = m & 1023;
        s16x4 pk;
        pk[0] = (short)f2bf(acc[mf][nf][0] + bv);
        pk[1] = (short)f2bf(acc[mf][nf][1] + bv);
        pk[2] = (short)f2bf(acc[mf][nf][2] + bv);
        pk[3] = (short)f2bf(acc[mf][nf][3] + bv);
        size_t idx = (((size_t)b * NH + h) * HD + d) * NS + s;
        *(s16x4*)&vt[idx] = pk;
      }
    }
  } else {
#pragma unroll
    for (int nf = 0; nf < 4; nf++) {
      int col = n0 + wc * 64 + nf * 16 + ll;
      float bv = bias[col];
      int w2 = col - which * ND;
      int h = w2 >> 6, d = w2 & 63;
#pragma unroll
      for (int mf = 0; mf < 4; mf++) {
#pragma unroll
        for (int r = 0; r < 4; r++) {
          int m = m0 + wr * 64 + mf * 16 + lh * 4 + r;
          int b = m >> 10, s = m & 1023;
          float v = acc[mf][nf][r] + bv;
          size_t idx = (((size_t)b * NH + h) * NS + s) * HD + d;
          if (which == 0)
            qw[idx] = f2bf(v * QSCALE);
          else
            kw[idx] = f2bf(v);
        }
      }
    }
  }
}

// ---------------- proj GEMM (unchanged) ----------------

__global__ __launch_bounds__(256, 3) void proj_gemm(const unsigned short* __restrict__ abf,
                                                    const unsigned short* __restrict__ WT,
                                                    const float* __restrict__ bias,
                                                    float* __restrict__ out) {
  __shared__ __align__(16) unsigned short smem[3 * SLOT];
  int bid = blockIdx.x;
  int k8 = bid & 7, j = bid >> 3;
  int m0 = (k8 * 8 + (j & 7)) * 128;
  int n0 = (j >> 3) * 128;
  f32x4 acc[4][4];
#pragma unroll
  for (int m = 0; m < 4; m++)
#pragma unroll
    for (int n = 0; n < 4; n++) acc[m][n] = (f32x4){0.f, 0.f, 0.f, 0.f};

  gemm_mainloop3(abf, WT, ND, m0, n0, smem, acc);

  int tid = threadIdx.x, lane = tid & 63, wid = tid >> 6;
  int wr = wid >> 1, wc = wid & 1;
  int ll = lane & 15, lh = lane >> 4;
#pragma unroll
  for (int nf = 0; nf < 4; nf++) {
    int col = n0 + wc * 64 + nf * 16 + ll;
    float bv = bias[col];
#pragma unroll
    for (int mf = 0; mf < 4; mf++) {
#pragma unroll
      for (int r = 0; r < 4; r++) {
        int m = m0 + wr * 64 + mf * 16 + lh * 4 + r;
        out[(size_t)m * ND + col] = acc[mf][nf][r] + bv;
      }
    }
  }
}

// ---------------- flash attention (r13-verified: XCD-grouped, log2 softmax) ----------------

#define LP 88          // Ps row stride (shorts)
#define KVSLOT 8192    // shorts: K[64][64] + V[64][64]

__global__ __launch_bounds__(512) void attn_kernel(const unsigned short* __restrict__ qw,
                                                   const unsigned short* __restrict__ kw,
                                                   const unsigned short* __restrict__ vt,
                                                   unsigned short* __restrict__ attn_out) {
  int bid = blockIdx.x;
  int xcd = bid & 7, j = bid >> 3;        // j in [0,96)
  int grp = xcd * 12 + (j % 12);          // bh group: 12 heads per XCD
  int qt = 7 - (j / 12);                  // heavy q-tiles first
  int b = grp / NH, h = grp % NH;
  __shared__ __align__(16) unsigned short KV[3 * KVSLOT];
  __shared__ __align__(16) unsigned short Ps[8][16 * LP];

  int tid = threadIdx.x, lane = tid & 63, wid = tid >> 6;
  int ll = lane & 15, lh = lane >> 4, r7x = ll & 7;
  int q0 = qt * 128, q0w = q0 + wid * 16;
  const size_t bhk = ((size_t)b * NH + h) * NS * HD;
  const size_t bhv = ((size_t)b * NH + h) * HD * NS;

  bf16x8 qf0 = ld8(&qw[bhk + (size_t)(q0w + ll) * HD + lh * 8]);
  bf16x8 qf1 = ld8(&qw[bhk + (size_t)(q0w + ll) * HD + 32 + lh * 8]);

  f32x4 o[4];
#pragma unroll
  for (int n = 0; n < 4; n++) o[n] = (f32x4){0.f, 0.f, 0.f, 0.f};
  float m_r = -1e30f, l_r = 0.f;

  int srow = tid >> 3;
  int scol = ((tid & 7) ^ ((tid >> 3) & 7)) * 8;
  const unsigned short* ksrc = kw + bhk + (size_t)srow * HD + scol;
  const unsigned short* vsrc = vt + bhv + (size_t)srow * NS + scol;

  unsigned short* pw = &Ps[wid][ll * LP];
  const int qme = q0w + ll;
  const int qmaxw = q0w + 15;
  const int nt = 2 * (qt + 1);

  auto stage = [&](int slot, int t) {
    unsigned short* kd = KV + slot * KVSLOT + wid * 512;
    unsigned short* vd = KV + slot * KVSLOT + 4096 + wid * 512;
    gload16(kd, ksrc + (size_t)t * 64 * HD);
    gload16(vd, vsrc + t * 64);
  };

  stage(0, 0);
  stage(1, 1);
  VMW(2);
  __builtin_amdgcn_s_barrier();
  asm volatile("" ::: "memory");

  int slot = 0;
  for (int t = 0; t < nt; ++t) {
    if (t + 2 < nt) {
      int s2 = slot + 2; if (s2 >= 3) s2 -= 3;
      stage(s2, t + 2);
    }
    int j0 = t * 64;

    if (j0 <= qmaxw) {
      const unsigned short* Kb = KV + slot * KVSLOT;
      const unsigned short* Vb = Kb + 4096;

      f32x4 sa[4];
#pragma unroll
      for (int n = 0; n < 4; n++) {
        bf16x8 kf0 = ld8(Kb + (n * 16 + ll) * 64 + (lh ^ r7x) * 8);
        bf16x8 kf1 = ld8(Kb + (n * 16 + ll) * 64 + ((4 + lh) ^ r7x) * 8);
        sa[n] = mfma16(kf0, qf0, (f32x4){0.f, 0.f, 0.f, 0.f});
        sa[n] = mfma16(kf1, qf1, sa[n]);
      }

      if (j0 + 63 > q0w) {
#pragma unroll
        for (int n = 0; n < 4; n++)
#pragma unroll
          for (int r = 0; r < 4; r++)
            if (j0 + n * 16 + lh * 4 + r > qme) sa[n][r] = -1e30f;
      }

      float t0 = fmaxf(fmaxf(sa[0][0], sa[0][1]), fmaxf(sa[0][2], sa[0][3]));
      float t1 = fmaxf(fmaxf(sa[1][0], sa[1][1]), fmaxf(sa[1][2], sa[1][3]));
      float t2 = fmaxf(fmaxf(sa[2][0], sa[2][1]), fmaxf(sa[2][2], sa[2][3]));
      float t3 = fmaxf(fmaxf(sa[3][0], sa[3][1]), fmaxf(sa[3][2], sa[3][3]));
      float tmax = fmaxf(fmaxf(t0, t1), fmaxf(t2, t3));
      tmax = fmaxf(tmax, __shfl_xor(tmax, 16));
      tmax = fmaxf(tmax, __shfl_xor(tmax, 32));

      // defer-max (log2 domain): skip rescale while growth <= 11.5 (P <= 2^11.5)
      if (!__all(tmax - m_r <= 11.5f)) {
        float mnew = fmaxf(m_r, tmax);
        float alpha = exp2f(m_r - mnew);
        m_r = mnew;
        l_r *= alpha;
        float ab0 = __shfl(alpha, lh * 4 + 0);
        float ab1 = __shfl(alpha, lh * 4 + 1);
        float ab2 = __shfl(alpha, lh * 4 + 2);
        float ab3 = __shfl(alpha, lh * 4 + 3);
#pragma unroll
        for (int n2 = 0; n2 < 4; n2++) {
          o[n2][0] *= ab0; o[n2][1] *= ab1; o[n2][2] *= ab2; o[n2][3] *= ab3;
        }
      }

      float p[4][4];
      float ssum = 0.f;
#pragma unroll
      for (int n = 0; n < 4; n++)
#pragma unroll
        for (int r = 0; r < 4; r++) {
          p[n][r] = exp2f(sa[n][r] - m_r);
          ssum += p[n][r];
        }
      ssum += __shfl_xor(ssum, 16);
      ssum += __shfl_xor(ssum, 32);
      l_r += ssum;

#pragma unroll
      for (int n = 0; n < 4; n++) {
        s16x4 pk;
        pk[0] = (short)f2bf(p[n][0]);
        pk[1] = (short)f2bf(p[n][1]);
        pk[2] = (short)f2bf(p[n][2]);
        pk[3] = (short)f2bf(p[n][3]);
        *(s16x4*)&pw[n * 16 + lh * 4] = pk;
      }

#pragma unroll
      for (int c = 0; c < 2; c++) {
        bf16x8 pf = ld8(&pw[c * 32 + lh * 8]);
#pragma unroll
        for (int n2 = 0; n2 < 4; n2++) {
          bf16x8 vf = ld8(Vb + (n2 * 16 + ll) * 64 + ((c * 4 + lh) ^ r7x) * 8);
          o[n2] = mfma16(pf, vf, o[n2]);
        }
      }
    }

    if (t + 2 < nt) {
      VMW(2);
      __builtin_amdgcn_s_barrier();
      asm volatile("" ::: "memory");
    } else if (t + 2 == nt) {
      VMW(0);
      __builtin_amdgcn_s_barrier();
      asm volatile("" ::: "memory");
    }
    slot++; if (slot == 3) slot = 0;
  }

  float lrec = 1.0f / l_r;
  float lb0 = __shfl(lrec, lh * 4 + 0);
  float lb1 = __shfl(lrec, lh * 4 + 1);
  float lb2 = __shfl(lrec, lh * 4 + 2);
  float lb3 = __shfl(lrec, lh * 4 + 3);
#pragma unroll
  for (int n2 = 0; n2 < 4; n2++) {
    int d = n2 * 16 + ll;
    int qb = q0w + lh * 4;
    attn_out[((size_t)b * NS + qb + 0) * ND + h * HD + d] = f2bf(o[n2][0] * lb0);
    attn_out[((size_t)b * NS + qb + 1) * ND + h * HD + d] = f2bf(o[n2][1] * lb1);
    attn_out[((size_t)b * NS + qb + 2) * ND + h * HD + d] = f2bf(o[n2][2] * lb2);
    attn_out[((size_t)b * NS + qb + 3) * ND + h * HD + d] = f2bf(o[n2][3] * lb3);
  }
}

// ---------------- launch ----------------

extern "C" void kernel_launch(void* const* d_in, const int* in_sizes, int n_in,
                              void* d_out, int out_size, void* d_ws, size_t ws_size,
                              hipStream_t stream) {
  const float* x = (const float*)d_in[0];
  const float* Wqkv = (const float*)d_in[1];
  const float* bqkv = (const float*)d_in[2];
  const float* Wproj = (const float*)d_in[3];
  const float* bproj = (const float*)d_in[4];
  float* out = (float*)d_out;

  char* ws = (char*)d_ws;
  const size_t SZ_X = (size_t)NB * NS * ND * 2;
  const size_t SZ_WQKV = (size_t)ND * 3 * ND * 2;
  const size_t SZ_WPROJ = (size_t)ND * ND * 2;
  const size_t SZ_HEAD = (size_t)NB * NH * NS * HD;  // elements

  unsigned short* xbf = (unsigned short*)(ws);
  unsigned short* wqkvT = (unsigned short*)(ws + SZ_X);
  unsigned short* wprojT = (unsigned short*)(ws + SZ_X + SZ_WQKV);
  unsigned short* qw = (unsigned short*)(ws + SZ_X + SZ_WQKV + SZ_WPROJ);
  unsigned short* kw = qw + SZ_HEAD;
  unsigned short* vt = kw + SZ_HEAD;   // V stored transposed [bh][d][s] by qkv_gemm
  unsigned short* attn = vt + SZ_HEAD;

  (void)in_sizes; (void)n_in; (void)out_size; (void)ws_size;

  cvt_f32_bf16<<<(NB * NS * ND) / 1024, 256, 0, stream>>>(x, xbf);
  transpose_cvt<<<dim3(3 * ND / 32, ND / 32), 256, 0, stream>>>(Wqkv, wqkvT, ND, 3 * ND);
  transpose_cvt<<<dim3(ND / 32, ND / 32), 256, 0, stream>>>(Wproj, wprojT, ND, ND);

  qkv_gemm<<<1152, 256, 0, stream>>>(xbf, wqkvT, bqkv, qw, kw, vt);

  attn_kernel<<<768, 512, 0, stream>>>(qw, kw, vt, attn);

  proj_gemm<<<384, 256, 0, stream>>>(attn, wprojT, bproj, out);
}